// Round 2
// baseline (1183.181 us; speedup 1.0000x reference)
//
#include <hip/hip_runtime.h>

#define NNET 32
#define NUNITS 2048
#define NEXC 1638
#define NINH 410

// ---------------------------------------------------------------------------
// Jobs 1-4: out[n,q] += sum_p W[n,p,q] * vec[n,p]   (contraction over p, q contiguous)
// Block decomposition: rel_blk -> (n, qb, pb). 256 threads, thread t -> q = qb*256+t.
// ---------------------------------------------------------------------------
__device__ __forceinline__ void col_matvec(const float* __restrict__ W,
                                           const float* __restrict__ r,
                                           float* __restrict__ acc,
                                           int rel_blk,
                                           int P, int Q, int QB, int PB, int PCH,
                                           int qoff, int vecoff) {
    int n   = rel_blk / (QB * PB);
    int rem = rel_blk % (QB * PB);
    int qb  = rem / PB;
    int pb  = rem % PB;

    int q  = qb * 256 + threadIdx.x;
    int p0 = pb * PCH;
    int p1 = min(p0 + PCH, P);
    int len = p1 - p0;

    __shared__ float s_r[256];            // PCH <= 205
    if ((int)threadIdx.x < len)
        s_r[threadIdx.x] = r[n * NUNITS + vecoff + p0 + threadIdx.x];
    __syncthreads();

    if (q >= Q) return;

    const float* Wp = W + ((size_t)n * P + p0) * Q + q;
    float a = 0.f;
    int p = 0;
    for (; p + 4 <= len; p += 4) {
        float w0 = Wp[(size_t)(p + 0) * Q];
        float w1 = Wp[(size_t)(p + 1) * Q];
        float w2 = Wp[(size_t)(p + 2) * Q];
        float w3 = Wp[(size_t)(p + 3) * Q];
        a += w0 * s_r[p] + w1 * s_r[p + 1] + w2 * s_r[p + 2] + w3 * s_r[p + 3];
    }
    for (; p < len; ++p)
        a += Wp[(size_t)p * Q] * s_r[p];

    atomicAdd(&acc[n * NUNITS + qoff + q], a);
}

// ---------------------------------------------------------------------------
// Job 5: inter_inh[i,a] = sum_{j,b} W_inter[i,j,a,b] * r_i[i,b]
// One wave per (i,a); rows are contiguous length-410 dot products (205 float2).
// ---------------------------------------------------------------------------
__device__ __forceinline__ void inter_job(const float* __restrict__ Wint,
                                          const float* __restrict__ r,
                                          float* __restrict__ acc,
                                          int rel_blk) {
    int i  = rel_blk / 103;   // 103 blocks per network (4 waves x 103 >= 410 a-values)
    int ab = rel_blk % 103;

    __shared__ float s_ri[NINH];
    for (int t = threadIdx.x; t < NINH; t += 256)
        s_ri[t] = r[i * NUNITS + NEXC + t];
    __syncthreads();

    int wave = threadIdx.x >> 6;
    int lane = threadIdx.x & 63;
    int a = ab * 4 + wave;
    if (a >= NINH) return;

    // W_inter[i][j][a][b]: index = ((i*NNET + j)*NINH + a)*NINH + b
    const float* base = Wint + ((size_t)i * NNET * NINH + a) * NINH;
    float accv = 0.f;
    for (int j = 0; j < NNET; ++j) {
        const float* row = base + (size_t)j * NINH * NINH;
        const float2* row2 = (const float2*)row;       // 8B-aligned: offset always even
        for (int b2 = lane; b2 < NINH / 2; b2 += 64) {
            float2 w = row2[b2];
            accv += w.x * s_ri[2 * b2] + w.y * s_ri[2 * b2 + 1];
        }
    }
    // wave reduce (64 lanes)
    for (int off = 32; off; off >>= 1)
        accv += __shfl_down(accv, off, 64);
    if (lane == 0)
        atomicAdd(&acc[i * NUNITS + NEXC + a], accv);
}

// ---------------------------------------------------------------------------
// Fused matvec kernel. Flat grid; ranges:
//   [0,1792)     W_ee: n=32, QB=7, PB=8
//   [1792,2240)  W_ie: n=32, QB=7, PB=2
//   [2240,2752)  W_ei: n=32, QB=2, PB=8
//   [2752,2880)  W_ii: n=32, QB=2, PB=2
//   [2880,6176)  W_inter: 32*103
// ---------------------------------------------------------------------------
__global__ __launch_bounds__(256) void fused_matvec(
    const float* __restrict__ Wee, const float* __restrict__ Wei,
    const float* __restrict__ Wie, const float* __restrict__ Wii,
    const float* __restrict__ Wint,
    const float* __restrict__ r, float* __restrict__ acc) {
    int blk = blockIdx.x;
    if (blk < 1792) {
        col_matvec(Wee, r, acc, blk,        1638, 1638, 7, 8, 205, 0,    0);
    } else if (blk < 2240) {
        col_matvec(Wie, r, acc, blk - 1792,  410, 1638, 7, 2, 205, 0,    NEXC);
    } else if (blk < 2752) {
        col_matvec(Wei, r, acc, blk - 2240, 1638,  410, 2, 8, 205, NEXC, 0);
    } else if (blk < 2880) {
        col_matvec(Wii, r, acc, blk - 2752,  410,  410, 2, 2, 205, NEXC, NEXC);
    } else {
        inter_job(Wint, r, acc, blk - 2880);
    }
}

// ---------------------------------------------------------------------------
// Finalize: r_new = 0.9*r + 0.1*relu(acc + unit_input)
// ---------------------------------------------------------------------------
__global__ __launch_bounds__(256) void finalize_kernel(
    const float* __restrict__ r, const float* __restrict__ uin,
    const float* __restrict__ acc, float* __restrict__ out) {
    int idx = blockIdx.x * 256 + threadIdx.x;
    if (idx < NNET * NUNITS) {
        float total = acc[idx] + uin[idx];
        float phi = fmaxf(total, 0.f);
        out[idx] = 0.9f * r[idx] + 0.1f * phi;
    }
}

extern "C" void kernel_launch(void* const* d_in, const int* in_sizes, int n_in,
                              void* d_out, int out_size, void* d_ws, size_t ws_size,
                              hipStream_t stream) {
    const float* unit_input = (const float*)d_in[0];
    const float* r          = (const float*)d_in[1];
    const float* W_ee       = (const float*)d_in[2];
    const float* W_ei       = (const float*)d_in[3];
    const float* W_ie       = (const float*)d_in[4];
    const float* W_ii       = (const float*)d_in[5];
    const float* W_inter    = (const float*)d_in[6];
    float* out = (float*)d_out;
    float* acc = (float*)d_ws;  // 32*2048 floats = 256 KB

    hipMemsetAsync(acc, 0, NNET * NUNITS * sizeof(float), stream);

    fused_matvec<<<6176, 256, 0, stream>>>(W_ee, W_ei, W_ie, W_ii, W_inter, r, acc);

    finalize_kernel<<<(NNET * NUNITS + 255) / 256, 256, 0, stream>>>(r, unit_input, acc, out);
}